// Round 9
// baseline (1719.656 us; speedup 1.0000x reference)
//
#include <hip/hip_runtime.h>
#include <hip/hip_bf16.h>

// ============================================================
// B=32, S=512, IN=3, H=64, D=128, NH=8, DH=16, L=4, C=5
// NSUB=10, MAX_CONSEC=50 -> SDE splits into 11 independent
// segments (state resets to enc at s % 51 == 0).
// Outputs (fp32): logits (160) then sde_features (32*512*64).
// R9: 27 dispatches -> 4. trans_kernel = persistent 256-block
// mega-kernel (input gemm + 4 layers + pool) with device-scope
// atomic grid barriers; setup2 = prep+encoder+precompute fused.
// sde_kernel byte-identical to R8 (442 us).
// ============================================================

typedef __attribute__((ext_vector_type(8))) short short8;
typedef __attribute__((ext_vector_type(4))) float f32x4;

// ---------------- ws layout (float element offsets) ----------------
static constexpr int OFF_TS      = 0;         // 49152
static constexpr int OFF_TIMES   = 49152;     // 16384
static constexpr int OFF_ENCW    = 65536;     // 192
static constexpr int OFF_ENCB    = 65728;     // 64
static constexpr int OFF_ENCG    = 65792;     // 64
static constexpr int OFF_ENCBETA = 65856;     // 64
static constexpr int OFF_DW1     = 65920;     // 8320 (65x128)
static constexpr int OFF_DB1     = 74240;     // 128
static constexpr int OFF_DW2     = 74368;     // 8192 (128x64)
static constexpr int OFF_DB2     = 82560;     // 64
static constexpr int OFF_DW3     = 82624;     // 4096 (64x64)
static constexpr int OFF_DB3     = 86720;     // 64
static constexpr int OFF_AW1     = 86784;     // 64
static constexpr int OFF_AB1     = 86848;     // 64
static constexpr int OFF_AW2     = 86912;     // 4096
static constexpr int OFF_AB2     = 91008;     // 64
static constexpr int OFF_BW1     = 91072;     // 64
static constexpr int OFF_BB1     = 91136;     // 64
static constexpr int OFF_BW2     = 91200;     // 4096
static constexpr int OFF_BB2     = 95296;     // 64
static constexpr int OFF_MD      = 95360;     // 1
static constexpr int OFF_INW     = 95424;     // 8192 (64x128)
static constexpr int OFF_INB     = 103616;    // 128
static constexpr int OFF_WQ      = 103744;    // 4*128*128
static constexpr int OFF_BQ      = 169280;    // 4*128
static constexpr int OFF_WK      = 169792;
static constexpr int OFF_BK      = 235328;
static constexpr int OFF_WV      = 235840;
static constexpr int OFF_BV      = 301376;
static constexpr int OFF_WO      = 301888;
static constexpr int OFF_BO      = 367424;
static constexpr int OFF_LN1G    = 367936;    // 4*128
static constexpr int OFF_LN1B    = 368448;
static constexpr int OFF_LN2G    = 368960;
static constexpr int OFF_LN2B    = 369472;
static constexpr int OFF_FW1     = 369984;    // 4*128*512
static constexpr int OFF_FB1     = 632128;    // 4*512
static constexpr int OFF_FW2     = 634176;    // 4*512*128
static constexpr int OFF_FB2     = 896320;    // 4*128
static constexpr int OFF_CW1     = 896832;    // 128*64
static constexpr int OFF_CB1     = 905024;    // 64
static constexpr int OFF_CW2     = 905088;    // 64*5 (pad)
static constexpr int OFF_CB2     = 905472;    // 5 (pad)
static constexpr int OFF_FLAG    = 905536;    // int flag: 1 = noise is bf16
// compute buffers
static constexpr int OFF_ENC     = 905600;    // 32*512*64 fp32
static constexpr int OFF_COEFA   = 3002752;   // 5110*64
static constexpr int OFF_COEFB   = 3329792;   // 5110*64
static constexpr int OFF_B1C     = 3656832;   // 5110*128
static constexpr int OFF_X       = 4310912;   // 16384*128 fp32 (residual master)
// bf16 buffers
static constexpr int OFF_XBF     = 6408064;   // 16384*128 bf16 (1048576 f)
static constexpr int OFF_QKVBF   = 7456640;   // 16384*384 bf16 (3145728 f)
static constexpr int OFF_OBF     = 10602368;  // 16384*128 bf16
static constexpr int OFF_HBF     = 11650944;  // 16384*512 bf16 (4194304 f)
static constexpr int OFF_SDEBF   = 15845248;  // 16384*64 bf16 (524288 f)
static constexpr int OFF_WQKVT   = 16369536;  // 4*384*128 bf16 (98304 f)
static constexpr int OFF_WOT     = 16467840;  // 4*128*128 bf16 (32768 f)
static constexpr int OFF_FW1T    = 16500608;  // 4*512*128 bf16 (131072 f)
static constexpr int OFF_FW2T    = 16631680;  // 4*128*512 bf16 (131072 f)
static constexpr int OFF_INWT    = 16762752;  // 128*64 bf16 (4096 f)
static constexpr int OFF_BQKV    = 16766848;  // 4*384 fp32
static constexpr int OFF_BAR     = 23185280;  // grid-barrier slots (128 u32)
// total = 25282432 floats ~= 96.5 MiB

struct PtrPack { const void* p[45]; };

// ---------------- helpers ----------------
__device__ inline float wsum64(float v) {
#pragma unroll
  for (int off = 32; off > 0; off >>= 1) v += __shfl_xor(v, off, 64);
  return v;
}

__device__ inline float fast_tanh(float x) {
  x = fminf(fmaxf(x, -15.f), 15.f);
  float e = __expf(2.f * x);
  return (e - 1.f) / (e + 1.f);
}

__device__ inline float tanh5(float x) {
  float e = __builtin_amdgcn_exp2f(x * 2.88539008f);
  return 1.f - 2.f * __builtin_amdgcn_rcpf(e + 1.f);
}

__device__ inline float bfdec(unsigned short h) {
  return __uint_as_float(((unsigned)h) << 16);
}

__device__ inline short f2bf(float f) {
  unsigned u = __float_as_uint(f);
  return (short)((u + 0x7FFFu + ((u >> 16) & 1u)) >> 16);
}

__device__ inline void lds_barrier() {
  asm volatile("s_waitcnt lgkmcnt(0)\ns_barrier" ::: "memory");
}

// device-scope grid barrier over 256 blocks; slot arrays pre-zeroed by ingest
__device__ inline void grid_barrier(unsigned* bar, int id) {
  __syncthreads();
  if (threadIdx.x == 0) {
    __threadfence();   // make this block's global writes visible (agent scope)
    unsigned old = __hip_atomic_fetch_add(&bar[id], 1u, __ATOMIC_ACQ_REL,
                                          __HIP_MEMORY_SCOPE_AGENT);
    if (old == 255u) {
      __hip_atomic_store(&bar[64 + id], 1u, __ATOMIC_RELEASE,
                         __HIP_MEMORY_SCOPE_AGENT);
    } else {
      while (!__hip_atomic_load(&bar[64 + id], __ATOMIC_ACQUIRE,
                                __HIP_MEMORY_SCOPE_AGENT))
        __builtin_amdgcn_s_sleep(8);
    }
    __threadfence();   // invalidate stale cached lines before consuming
  }
  __syncthreads();
}

// ---------------- dispatch 1: ingest (+ zero barrier slots) ----------------
__global__ __launch_bounds__(256) void ingest_kernel(PtrPack pk, float* __restrict__ W) {
  const int NE = 43;
  const int cnt[NE] = {49152,16384,192,64,64,64,8320,128,8192,64,4096,64,64,64,4096,64,
                       64,64,4096,64,1,8192,128,65536,512,65536,512,65536,512,65536,512,
                       512,512,512,512,262144,2048,262144,512,8192,64,320,5};
  const int src[NE] = {0,1,4,5,6,7,8,9,10,11,12,13,14,15,16,17,18,19,20,21,22,23,24,
                       25,26,27,28,29,30,31,32,33,34,35,36,37,38,39,40,41,42,43,44};
  const int dst[NE] = {OFF_TS,OFF_TIMES,OFF_ENCW,OFF_ENCB,OFF_ENCG,OFF_ENCBETA,OFF_DW1,
                       OFF_DB1,OFF_DW2,OFF_DB2,OFF_DW3,OFF_DB3,OFF_AW1,OFF_AB1,OFF_AW2,
                       OFF_AB2,OFF_BW1,OFF_BB1,OFF_BW2,OFF_BB2,OFF_MD,OFF_INW,OFF_INB,
                       OFF_WQ,OFF_BQ,OFF_WK,OFF_BK,OFF_WV,OFF_BV,OFF_WO,OFF_BO,
                       OFF_LN1G,OFF_LN1B,OFF_LN2G,OFF_LN2B,OFF_FW1,OFF_FB1,OFF_FW2,
                       OFF_FB2,OFF_CW1,OFF_CB1,OFF_CW2,OFF_CB2};
  const unsigned* eg = (const unsigned*)pk.p[6];     // enc_g (all ones)
  int gmode = (eg[0] == 0x3F803F80u) ? 1 : 0;

  __shared__ int isbf[NE];
  if (threadIdx.x < NE) {
    int k = threadIdx.x;
    int f = gmode;
    if (gmode) {
      const unsigned short* us = (const unsigned short*)pk.p[src[k]];
      int n = cnt[k] < 32 ? cnt[k] : 32;
      for (int i = 0; i < n; ++i) {
        unsigned short h = us[i];
        if (h & 0x7FFF) {
          float a = fabsf(bfdec(h));
          if (!(a > 1e-20f && a < 1e4f)) { f = 0; break; }
        }
      }
    }
    isbf[k] = f;
  }
  __syncthreads();

  int gid = blockIdx.x * 256 + threadIdx.x;
  int stride = gridDim.x * 256;
  if (gid < 128) ((unsigned*)(W + OFF_BAR))[gid] = 0u;   // barrier slots
  if (gid == 0) {
    int nf = gmode;
    if (gmode) {
      const unsigned short* us = (const unsigned short*)pk.p[2];
      for (int i = 0; i < 32; ++i) {
        unsigned short h = us[i];
        if (h & 0x7FFF) {
          float a = fabsf(bfdec(h));
          if (!(a > 1e-20f && a < 1e4f)) { nf = 0; break; }
        }
      }
    }
    ((int*)W)[OFF_FLAG] = nf;
  }
  for (int k = 0; k < NE; ++k) {
    int n = cnt[k];
    float* dp = W + dst[k];
    if (isbf[k]) {
      const unsigned short* us = (const unsigned short*)pk.p[src[k]];
      for (int e = gid; e < n; e += stride) dp[e] = bfdec(us[e]);
    } else {
      const float* fs = (const float*)pk.p[src[k]];
      for (int e = gid; e < n; e += stride) dp[e] = fs[e];
    }
  }
}

// ---------------- dispatch 2: prep + encoder + precompute fused ----------------
__global__ __launch_bounds__(256) void setup2_kernel(float* __restrict__ W,
                                                     float* __restrict__ outf) {
  const int bid = blockIdx.x;
  const int tid = threadIdx.x;
  __shared__ float av2[2][64], bv2[2][64];

  if (bid < 128) {
    // ---- prep: transpose transformer weights to bf16 N-major ----
    short* wqkvT = (short*)(W + OFF_WQKVT);
    short* woT   = (short*)(W + OFF_WOT);
    short* fw1T  = (short*)(W + OFF_FW1T);
    short* fw2T  = (short*)(W + OFF_FW2T);
    short* inwT  = (short*)(W + OFF_INWT);
    float* bqkv  = W + OFF_BQKV;
    int gid = bid * 256 + tid;
    int stride = 128 * 256;
    for (int e = gid; e < 796160; e += stride) {
      if (e < 196608) {            // wqkvT[l][384][128]
        int l = e / 49152, r = e % 49152, n = r >> 7, k = r & 127;
        float v = (n < 128) ? W[OFF_WQ + l*16384 + k*128 + n]
                : (n < 256) ? W[OFF_WK + l*16384 + k*128 + (n - 128)]
                            : W[OFF_WV + l*16384 + k*128 + (n - 256)];
        wqkvT[e] = f2bf(v);
      } else if (e < 262144) {     // woT[l][128][128]
        int t = e - 196608; int l = t / 16384, r = t % 16384, n = r >> 7, k = r & 127;
        woT[t] = f2bf(W[OFF_WO + l*16384 + k*128 + n]);
      } else if (e < 524288) {     // fw1T[l][512][128]
        int t = e - 262144; int l = t / 65536, r = t % 65536, n = r >> 7, k = r & 127;
        fw1T[t] = f2bf(W[OFF_FW1 + l*65536 + k*512 + n]);
      } else if (e < 786432) {     // fw2T[l][128][512]
        int t = e - 524288; int l = t / 65536, r = t % 65536, n = r >> 9, k = r & 511;
        fw2T[t] = f2bf(W[OFF_FW2 + l*65536 + k*128 + n]);
      } else if (e < 794624) {     // inwT[128][64]
        int t = e - 786432; int n = t >> 6, k = t & 63;
        inwT[t] = f2bf(W[OFF_INW + k*128 + n]);
      } else {                     // bqkv[4][384] fp32
        int t = e - 794624; int l = t / 384, j = t % 384;
        bqkv[t] = (j < 128) ? W[OFF_BQ + l*128 + j]
                : (j < 256) ? W[OFF_BK + l*128 + (j - 128)]
                            : W[OFF_BV + l*128 + (j - 256)];
      }
    }
  } else if (bid < 768) {
    // ---- encoder: enc = relu(LN(ts @ enc_w + enc_b)); 640 blocks x 4 waves ----
    int w = tid >> 6, j = tid & 63;
    for (int row = (bid - 128)*4 + w; row < 16384; row += 640*4) {
      float t0 = W[OFF_TS + row*3 + 0];
      float t1 = W[OFF_TS + row*3 + 1];
      float t2 = W[OFF_TS + row*3 + 2];
      float v = W[OFF_ENCB + j] + t0 * W[OFF_ENCW + j] + t1 * W[OFF_ENCW + 64 + j]
              + t2 * W[OFF_ENCW + 128 + j];
      float mean = wsum64(v) * (1.f / 64.f);
      float d = v - mean;
      float var = wsum64(d * d) * (1.f / 64.f);
      float o = d * rsqrtf(var + 1e-5f) * W[OFF_ENCG + j] + W[OFF_ENCBETA + j];
      o = fmaxf(o, 0.f);
      W[OFF_ENC + row*64 + j] = o;
      int s = row & 511;
      if (s % 51 == 0) {   // reset positions: sde_features[:,s] = enc[:,s]
        ((short*)(W + OFF_SDEBF))[row*64 + j] = f2bf(o);
        outf[160 + row*64 + j] = o;
      }
    }
  } else {
    // ---- precompute A(t), Bt(t), bias1(t); 512 blocks x 2 jobs ----
    int half = tid >> 7, lt = tid & 127;
    for (int base = (bid - 768)*2; base < 5110; base += 1024) {
      int bi = base + half;
      bool act = bi < 5110;
      float t = 0.f;
      if (act) {
        int step = bi / 10, k = bi - step * 10;
        float t_prev = W[OFF_TIMES + step];
        float t_cur  = W[OFF_TIMES + step + 1];
        float h = (t_cur - t_prev) * 0.1f;
        t = t_prev + (float)k * h;
        if (lt < 64) av2[half][lt] = fast_tanh(t * W[OFF_AW1 + lt] + W[OFF_AB1 + lt]);
        else { int j = lt - 64; bv2[half][j] = fast_tanh(t * W[OFF_BW1 + j] + W[OFF_BB1 + j]); }
      }
      __syncthreads();
      if (act) {
        if (lt < 64) {
          float a = W[OFF_AB2 + lt];
          for (int i = 0; i < 64; ++i) a += av2[half][i] * W[OFF_AW2 + i*64 + lt];
          W[OFF_COEFA + bi*64 + lt] = fmaxf(a, 0.f) + log1pf(__expf(-fabsf(a)));
        } else {
          int j = lt - 64;
          float a = W[OFF_BB2 + j];
          for (int i = 0; i < 64; ++i) a += bv2[half][i] * W[OFF_BW2 + i*64 + j];
          W[OFF_COEFB + bi*64 + j] = fast_tanh(a);
        }
        W[OFF_B1C + bi*128 + lt] = t * W[OFF_DW1 + 64*128 + lt] + W[OFF_DB1 + lt];
      }
      __syncthreads();
    }
  }
}

// ---------------- dispatch 3: SDE integrator (identical to R8) ----------------
__global__ __launch_bounds__(256, 1) void sde_kernel(float* __restrict__ W,
                                                     const void* __restrict__ noise,
                                                     float* __restrict__ outf) {
  __shared__ short ybf[16 * 72];
  __shared__ short h1bf[16 * 136];
  __shared__ short h2bf[16 * 72];

  const int tid = threadIdx.x;
  const int w   = tid >> 6;
  const int lane = tid & 63;
  const int q   = lane >> 4;
  const int lq  = lane & 15;
  const int g   = blockIdx.x >> 1;
  const int r0  = (blockIdx.x & 1) * 16;

  const int nmode = ((const int*)W)[OFF_FLAG];
  const float md = fabsf(W[OFF_MD]);
  const unsigned short* nb16 = (const unsigned short*)noise;
  const float* nf32 = (const float*)noise;
  short* sdebf = (short*)(W + OFF_SDEBF);

  const int ncol = w*16 + lq;
  short8 B1f[2][2];
#pragma unroll
  for (int kt = 0; kt < 2; ++kt)
#pragma unroll
    for (int ct = 0; ct < 2; ++ct)
#pragma unroll
      for (int j = 0; j < 8; ++j)
        B1f[kt][ct][j] = f2bf(W[OFF_DW1 + (kt*32 + q*8 + j)*128 + w*32 + ct*16 + lq]);
  short8 B2f[4];
#pragma unroll
  for (int kt = 0; kt < 4; ++kt)
#pragma unroll
    for (int j = 0; j < 8; ++j)
      B2f[kt][j] = f2bf(W[OFF_DW2 + (kt*32 + q*8 + j)*64 + ncol]);
  short8 B3f[2];
#pragma unroll
  for (int kt = 0; kt < 2; ++kt)
#pragma unroll
    for (int j = 0; j < 8; ++j)
      B3f[kt][j] = f2bf(W[OFF_DW3 + (kt*32 + q*8 + j)*64 + ncol]);
  const float db2v = W[OFF_DB2 + ncol];
  const float db3v = W[OFF_DB3 + ncol];

  float yreg[4];
#pragma unroll
  for (int r = 0; r < 4; ++r) {
    yreg[r] = W[OFF_ENC + ((r0 + q*4 + r)*512 + 51*g)*64 + ncol];
    ybf[(q*4 + r)*72 + ncol] = f2bf(yreg[r]);
  }

  const int ci0 = 51*g*10;
  float bias_a = W[OFF_B1C + ci0*128 + w*32 + lq];
  float bias_b = W[OFF_B1C + ci0*128 + w*32 + 16 + lq];
  float ca = W[OFF_COEFA + ci0*64 + ncol];
  float cb = W[OFF_COEFB + ci0*64 + ncol];

  const int nsteps = (g == 10) ? 1 : 50;
  for (int m = 0; m < nsteps; ++m) {
    const int istep = 51*g + m;
    const float t_prev = W[OFF_TIMES + istep];
    const float t_cur  = W[OFF_TIMES + istep + 1];
    const float hstep = (t_cur - t_prev) * 0.1f;
    const float sqh = sqrtf(hstep);
    for (int k = 0; k < 10; ++k) {
      const int ci = istep*10 + k;
      const int cin = (ci + 1 > 5109) ? 5109 : ci + 1;
      float b1na = W[OFF_B1C + cin*128 + w*32 + lq];
      float b1nb = W[OFF_B1C + cin*128 + w*32 + 16 + lq];
      float can = W[OFF_COEFA + cin*64 + ncol];
      float cbn = W[OFF_COEFB + cin*64 + ncol];
      float dwv[4];
      {
        const int nb = (((istep + 1)*10 + k)*32 + r0 + q*4)*64 + ncol;
#pragma unroll
        for (int r = 0; r < 4; ++r)
          dwv[r] = nmode ? bfdec(nb16[nb + r*64]) : nf32[nb + r*64];
      }
      lds_barrier();
      {
        short8 a0 = *(const short8*)&ybf[lq*72 + q*8];
        short8 a1 = *(const short8*)&ybf[lq*72 + 32 + q*8];
        f32x4 c0 = {bias_a, bias_a, bias_a, bias_a};
        c0 = __builtin_amdgcn_mfma_f32_16x16x32_bf16(a0, B1f[0][0], c0, 0, 0, 0);
        c0 = __builtin_amdgcn_mfma_f32_16x16x32_bf16(a1, B1f[1][0], c0, 0, 0, 0);
        f32x4 c1 = {bias_b, bias_b, bias_b, bias_b};
        c1 = __builtin_amdgcn_mfma_f32_16x16x32_bf16(a0, B1f[0][1], c1, 0, 0, 0);
        c1 = __builtin_amdgcn_mfma_f32_16x16x32_bf16(a1, B1f[1][1], c1, 0, 0, 0);
#pragma unroll
        for (int r = 0; r < 4; ++r) {
          h1bf[(q*4 + r)*136 + w*32 + lq]      = f2bf(tanh5(c0[r]));
          h1bf[(q*4 + r)*136 + w*32 + 16 + lq] = f2bf(tanh5(c1[r]));
        }
      }
      lds_barrier();
      {
        short8 h0 = *(const short8*)&h1bf[lq*136 + q*8];
        short8 h1 = *(const short8*)&h1bf[lq*136 + 32 + q*8];
        short8 h2 = *(const short8*)&h1bf[lq*136 + 64 + q*8];
        short8 h3 = *(const short8*)&h1bf[lq*136 + 96 + q*8];
        f32x4 cA = {db2v, db2v, db2v, db2v};
        cA = __builtin_amdgcn_mfma_f32_16x16x32_bf16(h0, B2f[0], cA, 0, 0, 0);
        cA = __builtin_amdgcn_mfma_f32_16x16x32_bf16(h1, B2f[1], cA, 0, 0, 0);
        f32x4 cB = {0.f, 0.f, 0.f, 0.f};
        cB = __builtin_amdgcn_mfma_f32_16x16x32_bf16(h2, B2f[2], cB, 0, 0, 0);
        cB = __builtin_amdgcn_mfma_f32_16x16x32_bf16(h3, B2f[3], cB, 0, 0, 0);
#pragma unroll
        for (int r = 0; r < 4; ++r)
          h2bf[(q*4 + r)*72 + ncol] = f2bf(tanh5(cA[r] + cB[r]));
      }
      lds_barrier();
      {
        short8 g0 = *(const short8*)&h2bf[lq*72 + q*8];
        short8 g1 = *(const short8*)&h2bf[lq*72 + 32 + q*8];
        f32x4 d = {db3v, db3v, db3v, db3v};
        d = __builtin_amdgcn_mfma_f32_16x16x32_bf16(g0, B3f[0], d, 0, 0, 0);
        d = __builtin_amdgcn_mfma_f32_16x16x32_bf16(g1, B3f[1], d, 0, 0, 0);
#pragma unroll
        for (int r = 0; r < 4; ++r) {
          float yv = yreg[r];
          yv = yv + d[r]*hstep + (ca + cb*yv + md)*sqh*dwv[r];
          yreg[r] = yv;
          ybf[(q*4 + r)*72 + ncol] = f2bf(yv);
        }
      }
      bias_a = b1na; bias_b = b1nb; ca = can; cb = cbn;
    }
#pragma unroll
    for (int r = 0; r < 4; ++r) {
      const int gi = ((r0 + q*4 + r)*512 + (istep + 1))*64 + ncol;
      sdebf[gi] = f2bf(yreg[r]);
      outf[160 + gi] = yreg[r];
    }
  }
}

// ================ trans_kernel phase bodies (device functions) ================

// 128x128-tile GEMM job, bf16 out only. sm: 2*128*40 shorts.
__device__ void gemm128_job(const short* __restrict__ A, const short* __restrict__ BT,
                            const float* __restrict__ bias, short* __restrict__ Cb,
                            int N, int K, int relu, int bm, int bn,
                            short* __restrict__ sm) {
  short* As = sm;
  short* Bs = sm + 128*40;
  const int tid = threadIdx.x;
  const int w = tid >> 6, lane = tid & 63, q = lane >> 4, lq = lane & 15;
  const int wm = (w >> 1) * 64, wn = (w & 1) * 64;
  const int arow = tid >> 1, ah = (tid & 1) * 16;
  f32x4 acc[4][4];
#pragma unroll
  for (int i = 0; i < 4; ++i)
#pragma unroll
    for (int j = 0; j < 4; ++j) acc[i][j] = (f32x4){0.f, 0.f, 0.f, 0.f};

  for (int k0 = 0; k0 < K; k0 += 32) {
    short8 a0 = *(const short8*)&A[(bm + arow)*K + k0 + ah];
    short8 a1 = *(const short8*)&A[(bm + arow)*K + k0 + ah + 8];
    short8 b0 = *(const short8*)&BT[(bn + arow)*K + k0 + ah];
    short8 b1 = *(const short8*)&BT[(bn + arow)*K + k0 + ah + 8];
    __syncthreads();
    *(short8*)&As[arow*40 + ah]     = a0;
    *(short8*)&As[arow*40 + ah + 8] = a1;
    *(short8*)&Bs[arow*40 + ah]     = b0;
    *(short8*)&Bs[arow*40 + ah + 8] = b1;
    __syncthreads();
    short8 af[4], bf[4];
#pragma unroll
    for (int mi = 0; mi < 4; ++mi)
      af[mi] = *(const short8*)&As[(wm + mi*16 + lq)*40 + q*8];
#pragma unroll
    for (int ni = 0; ni < 4; ++ni)
      bf[ni] = *(const short8*)&Bs[(wn + ni*16 + lq)*40 + q*8];
#pragma unroll
    for (int mi = 0; mi < 4; ++mi)
#pragma unroll
      for (int ni = 0; ni < 4; ++ni)
        acc[mi][ni] = __builtin_amdgcn_mfma_f32_16x16x32_bf16(af[mi], bf[ni],
                                                              acc[mi][ni], 0, 0, 0);
  }
#pragma unroll
  for (int ni = 0; ni < 4; ++ni) {
    const int col = bn + wn + ni*16 + lq;
    const float bv = bias ? bias[col] : 0.f;
#pragma unroll
    for (int mi = 0; mi < 4; ++mi) {
#pragma unroll
      for (int r = 0; r < 4; ++r) {
        const int row = bm + wm + mi*16 + q*4 + r;
        float v = acc[mi][ni][r] + bv;
        if (relu) v = fmaxf(v, 0.f);
        Cb[row*N + col] = f2bf(v);
      }
    }
  }
}

// M64 GEMM, N=128, optional fused residual+LN. sm: 64*40 + 128*40 shorts.
__device__ void ln64_job(const short* __restrict__ A, const short* __restrict__ BT,
                         const float* __restrict__ bias, float* __restrict__ X,
                         short* __restrict__ Xb, int K,
                         const float* __restrict__ lng, const float* __restrict__ lnb,
                         int bid, short* __restrict__ sm) {
  short* As = sm;              // 64*40
  short* Bs = sm + 64*40;      // 128*40
  const int tid = threadIdx.x;
  const int w = tid >> 6, lane = tid & 63, q = lane >> 4, lq = lane & 15;
  const int bm = bid * 64;
  f32x4 acc[8];
#pragma unroll
  for (int i = 0; i < 8; ++i) acc[i] = (f32x4){0.f, 0.f, 0.f, 0.f};

  const int arow = tid >> 2, acol = (tid & 3) * 8;
  const int brow = tid >> 1, bcol = (tid & 1) * 16;
  for (int k0 = 0; k0 < K; k0 += 32) {
    short8 a  = *(const short8*)&A[(bm + arow)*K + k0 + acol];
    short8 b0 = *(const short8*)&BT[brow*K + k0 + bcol];
    short8 b1 = *(const short8*)&BT[brow*K + k0 + bcol + 8];
    __syncthreads();
    *(short8*)&As[arow*40 + acol]    = a;
    *(short8*)&Bs[brow*40 + bcol]    = b0;
    *(short8*)&Bs[brow*40 + bcol+8]  = b1;
    __syncthreads();
    short8 af = *(const short8*)&As[(w*16 + lq)*40 + q*8];
#pragma unroll
    for (int ni = 0; ni < 8; ++ni) {
      short8 bf = *(const short8*)&Bs[(ni*16 + lq)*40 + q*8];
      acc[ni] = __builtin_amdgcn_mfma_f32_16x16x32_bf16(af, bf, acc[ni], 0, 0, 0);
    }
  }
  if (lng == nullptr) {
#pragma unroll
    for (int r = 0; r < 4; ++r) {
      const int row = bm + w*16 + q*4 + r;
#pragma unroll
      for (int ni = 0; ni < 8; ++ni) {
        const int col = ni*16 + lq;
        float v = acc[ni][r] + bias[col];
        X[row*128 + col] = v;
        Xb[row*128 + col] = f2bf(v);
      }
    }
  } else {
#pragma unroll
    for (int r = 0; r < 4; ++r) {
      const int row = bm + w*16 + q*4 + r;
      float v[8];
      float s = 0.f, s2 = 0.f;
#pragma unroll
      for (int ni = 0; ni < 8; ++ni) {
        const int col = ni*16 + lq;
        float t = acc[ni][r] + bias[col] + X[row*128 + col];
        v[ni] = t; s += t; s2 += t*t;
      }
#pragma unroll
      for (int off = 1; off < 16; off <<= 1) {
        s  += __shfl_xor(s, off, 16);
        s2 += __shfl_xor(s2, off, 16);
      }
      float mean = s * (1.f / 128.f);
      float var = s2 * (1.f / 128.f) - mean * mean;
      float inv = rsqrtf(var + 1e-5f);
#pragma unroll
      for (int ni = 0; ni < 8; ++ni) {
        const int col = ni*16 + lq;
        float o = (v[ni] - mean) * inv * lng[col] + lnb[col];
        X[row*128 + col] = o;
        Xb[row*128 + col] = f2bf(o);
      }
    }
  }
}

// attention for one (b,h). sm: Kt 512*20 + Vt 16*520 + Pb 4*16*136 shorts.
__device__ void attn_job(const short* __restrict__ QKV, short* __restrict__ O,
                         int bid, short* __restrict__ sm) {
  short* Kt = sm;                    // 10240 shorts
  short* Vt = sm + 10240;            // 8320 shorts
  short* Pb = sm + 18560;            // 8704 shorts
  const int h = bid & 7, b = bid >> 3;
  const int tid = threadIdx.x;
  const int w = tid >> 6, lane = tid & 63, q = lane >> 4, lq = lane & 15;

#pragma unroll
  for (int kk = 0; kk < 2; ++kk) {
    const int key = tid + kk*256;
    const short* src = &QKV[(size_t)(b*512 + key)*384 + 128 + h*16];
    short8 k0 = *(const short8*)src;
    short8 k1 = *(const short8*)(src + 8);
    *(short8*)&Kt[key*20]     = k0;
    *(short8*)&Kt[key*20 + 8] = k1;
    short8 v0 = *(const short8*)(src + 128);
    short8 v1 = *(const short8*)(src + 136);
#pragma unroll
    for (int d = 0; d < 8; ++d) Vt[d*520 + key] = v0[d];
#pragma unroll
    for (int d = 0; d < 8; ++d) Vt[(8 + d)*520 + key] = v1[d];
  }
  __syncthreads();

  short* Pw = &Pb[w * 2176];
  const float cexp = 0.25f * 1.44269504f;

  for (int qi = 0; qi < 8; ++qi) {
    const int qrow0 = b*512 + (w*8 + qi)*16;
    short8 aq = (short8){0,0,0,0,0,0,0,0};
    if (q < 2) aq = *(const short8*)&QKV[(size_t)(qrow0 + lq)*384 + h*16 + q*8];

    f32x4 acc[32];
#pragma unroll
    for (int t = 0; t < 32; ++t) {
      short8 bk = (short8){0,0,0,0,0,0,0,0};
      if (q < 2) bk = *(const short8*)&Kt[(t*16 + lq)*20 + q*8];
      f32x4 z = {0.f, 0.f, 0.f, 0.f};
      acc[t] = __builtin_amdgcn_mfma_f32_16x16x32_bf16(aq, bk, z, 0, 0, 0);
    }
    float mx[4] = {-1e30f, -1e30f, -1e30f, -1e30f};
#pragma unroll
    for (int t = 0; t < 32; ++t)
#pragma unroll
      for (int r = 0; r < 4; ++r) mx[r] = fmaxf(mx[r], acc[t][r]);
#pragma unroll
    for (int off = 1; off < 16; off <<= 1)
#pragma unroll
      for (int r = 0; r < 4; ++r) mx[r] = fmaxf(mx[r], __shfl_xor(mx[r], off, 16));
    float ls[4] = {0.f, 0.f, 0.f, 0.f};
#pragma unroll
    for (int t = 0; t < 32; ++t)
#pragma unroll
      for (int r = 0; r < 4; ++r) {
        float p = __builtin_amdgcn_exp2f((acc[t][r] - mx[r]) * cexp);
        acc[t][r] = p;
        ls[r] += p;
      }
#pragma unroll
    for (int off = 1; off < 16; off <<= 1)
#pragma unroll
      for (int r = 0; r < 4; ++r) ls[r] += __shfl_xor(ls[r], off, 16);

    f32x4 o = {0.f, 0.f, 0.f, 0.f};
#pragma unroll
    for (int c = 0; c < 4; ++c) {
#pragma unroll
      for (int tt = 0; tt < 8; ++tt)
#pragma unroll
        for (int r = 0; r < 4; ++r)
          Pw[(q*4 + r)*136 + tt*16 + lq] =
              (short)(__float_as_uint(acc[c*8 + tt][r]) >> 16);
#pragma unroll
      for (int kk = 0; kk < 4; ++kk) {
        short8 ap = *(const short8*)&Pw[lq*136 + kk*32 + q*8];
        short8 bv = *(const short8*)&Vt[lq*520 + c*128 + kk*32 + q*8];
        o = __builtin_amdgcn_mfma_f32_16x16x32_bf16(ap, bv, o, 0, 0, 0);
      }
    }
#pragma unroll
    for (int r = 0; r < 4; ++r) {
      float ov = o[r] * __builtin_amdgcn_rcpf(ls[r]);
      O[(size_t)(qrow0 + q*4 + r)*128 + h*16 + lq] = f2bf(ov);
    }
  }
}

// mean-pool + classifier for one batch row b. psm: 192 floats.
__device__ void pool_job(const float* __restrict__ W, float* __restrict__ outf,
                         int b, float* __restrict__ psm) {
  const int j = threadIdx.x;
  float* pooled = psm;
  float* hid = psm + 128;
  if (j < 128) {
    float s0 = 0.f, s1 = 0.f, s2 = 0.f, s3 = 0.f;
    const float* xb = W + OFF_X + b*512*128 + j;
    for (int ss = 0; ss < 128; ++ss) {
      s0 += xb[ss*128];
      s1 += xb[(128 + ss)*128];
      s2 += xb[(256 + ss)*128];
      s3 += xb[(384 + ss)*128];
    }
    pooled[j] = (s0 + s1 + s2 + s3) * (1.f / 512.f);
  }
  __syncthreads();
  if (j < 64) {
    float a = W[OFF_CB1 + j];
    for (int i = 0; i < 128; ++i) a += pooled[i] * W[OFF_CW1 + i*64 + j];
    hid[j] = fmaxf(a, 0.f);
  }
  __syncthreads();
  if (j < 5) {
    float a = W[OFF_CB2 + j];
    for (int i = 0; i < 64; ++i) a += hid[i] * W[OFF_CW2 + i*5 + j];
    outf[b*5 + j] = a;
  }
}

// ---------------- dispatch 4: persistent transformer mega-kernel ----------------
__global__ __launch_bounds__(256, 2) void trans_kernel(float* __restrict__ W,
                                                       float* __restrict__ outf) {
  __shared__ __align__(16) short sm[27264];   // 54.5 KB arena (max phase: attn)
  unsigned* bar = (unsigned*)(W + OFF_BAR);
  const int bid = blockIdx.x;                 // 256 blocks

  short* sdebf = (short*)(W + OFF_SDEBF);
  short* xbf   = (short*)(W + OFF_XBF);
  short* qkvbf = (short*)(W + OFF_QKVBF);
  short* obf   = (short*)(W + OFF_OBF);
  short* hbf   = (short*)(W + OFF_HBF);

  // P0: x = sde_features @ in_w + in_b
  ln64_job(sdebf, (short*)(W + OFF_INWT), W + OFF_INB, W + OFF_X, xbf, 64,
           nullptr, nullptr, bid, sm);
  grid_barrier(bar, 0);

  for (int l = 0; l < 4; ++l) {
    // qkv: 384 tile-jobs of 128x128
    for (int j = bid; j < 384; j += 256)
      gemm128_job(xbf, (short*)(W + OFF_WQKVT) + l*49152, W + OFF_BQKV + l*384,
                  qkvbf, 384, 128, 0, (j & 127)*128, (j >> 7)*128, sm);
    grid_barrier(bar, 1 + l*5);
    // attention
    attn_job(qkvbf, obf, bid, sm);
    grid_barrier(bar, 2 + l*5);
    // wo + residual + LN1
    ln64_job(obf, (short*)(W + OFF_WOT) + l*16384, W + OFF_BO + l*128,
             W + OFF_X, xbf, 128, W + OFF_LN1G + l*128, W + OFF_LN1B + l*128,
             bid, sm);
    grid_barrier(bar, 3 + l*5);
    // fw1 (relu): 512 tile-jobs, exactly 2 per block
    for (int j = bid; j < 512; j += 256)
      gemm128_job(xbf, (short*)(W + OFF_FW1T) + l*65536, W + OFF_FB1 + l*512,
                  hbf, 512, 128, 1, (j & 127)*128, (j >> 7)*128, sm);
    grid_barrier(bar, 4 + l*5);
    // fw2 + residual + LN2
    ln64_job(hbf, (short*)(W + OFF_FW2T) + l*65536, W + OFF_FB2 + l*128,
             W + OFF_X, xbf, 512, W + OFF_LN2G + l*128, W + OFF_LN2B + l*128,
             bid, sm);
    grid_barrier(bar, 5 + l*5);
  }

  if (bid < 32) pool_job(W, outf, bid, (float*)sm);
}

// ---------------- launch ----------------
extern "C" void kernel_launch(void* const* d_in, const int* in_sizes, int n_in,
                              void* d_out, int out_size, void* d_ws, size_t ws_size,
                              hipStream_t stream) {
  (void)in_sizes; (void)out_size; (void)ws_size;
  float* W = reinterpret_cast<float*>(d_ws);
  float* outf = reinterpret_cast<float*>(d_out);
  PtrPack pk;
  for (int i = 0; i < 45 && i < n_in; ++i) pk.p[i] = d_in[i];

  ingest_kernel<<<512, 256, 0, stream>>>(pk, W);
  setup2_kernel<<<1280, 256, 0, stream>>>(W, outf);
  sde_kernel<<<22, 256, 0, stream>>>(W, d_in[2], outf);
  trans_kernel<<<256, 256, 0, stream>>>(W, outf);
}